// Round 19
// baseline (104.972 us; speedup 1.0000x reference)
//
#include <hip/hip_runtime.h>
#include <hip/hip_bf16.h>

// ALiBi attention, B=8 L=1024 H=8 E=64, fp32 in/out, bf16 MFMA inside.
// Outputs: V [B,L,H,E] then series [B,H,L,L] concatenated in d_out.
// R19: three-kernel decomposition.
//  prep_kv: K->bf16, V->bf16 V^T, gload-linear swizzled chunks (as R12).
//  z_pass:  grid 4096 (16 qb x 4 key-quarters x 64 bh): z-partials to
//           zp[ks][bh][q] in d_ws. Per-block chain = 4 chunks; 16KB LDS ->
//           8 blocks/CU. The latency-bound phase gets 4x parallelism.
//  p_pass:  R12's pass B verbatim (champion code) + z-sum prologue;
//           standalone write-bound stream. O-store plain (not NT).

typedef short short8 __attribute__((ext_vector_type(8)));
typedef short short4v __attribute__((ext_vector_type(4)));
typedef float f32x4 __attribute__((ext_vector_type(4)));
typedef unsigned short u16x4 __attribute__((ext_vector_type(4)));

#define B_ 8
#define L_ 1024
#define H_ 8
#define E_ 64
#define RSTRIDE (H_ * E_)       // 512 floats between seq rows
#define QBLK 64                 // 4 waves x 16 q-rows
#define CHUNK 64                // keys per chunk
#define NCH (L_ / CHUNK)        // 16
#define CHUNK_USH (CHUNK * E_)  // 4096 ushorts = 8KB per chunk tile

__device__ __forceinline__ unsigned short f2bf(float f) {
  return __builtin_bit_cast(unsigned short, __float2bfloat16(f));
}
__device__ __forceinline__ short8 ldfrag(const float* p) {
  float4 a = *reinterpret_cast<const float4*>(p);
  float4 b = *reinterpret_cast<const float4*>(p + 4);
  return (short8){(short)f2bf(a.x), (short)f2bf(a.y), (short)f2bf(a.z),
                  (short)f2bf(a.w), (short)f2bf(b.x), (short)f2bf(b.y),
                  (short)f2bf(b.z), (short)f2bf(b.w)};
}

__device__ __forceinline__ f32x4 mfma16(short4v a, short4v b, f32x4 c) {
#if __has_builtin(__builtin_amdgcn_mfma_f32_16x16x16bf16_1k)
  return __builtin_amdgcn_mfma_f32_16x16x16bf16_1k(a, b, c, 0, 0, 0);
#else
  asm volatile(
      "s_nop 1\n\t"
      "v_mfma_f32_16x16x16_bf16 %0, %1, %2, %0\n\t"
      "s_nop 2"
      : "+v"(c)
      : "v"(a), "v"(b));
  return c;
#endif
}

__device__ __forceinline__ void gld16(const unsigned short* g,
                                      unsigned short* l) {
  __builtin_amdgcn_global_load_lds(
      (const __attribute__((address_space(1))) unsigned int*)g,
      (__attribute__((address_space(3))) unsigned int*)l, 16, 0, 0);
}

#define BAR_VM(N)                                         \
  {                                                       \
    asm volatile("s_waitcnt vmcnt(" #N ")" ::: "memory"); \
    __builtin_amdgcn_s_barrier();                         \
    __builtin_amdgcn_sched_barrier(0);                    \
  }
#define PIN() __builtin_amdgcn_sched_barrier(0)

// ---- prep: scratch in gload-linear swizzled block order ----
// K chunk (64 s x 64 e): 16B-block j <-> (s = j>>3, e8 = (j&7)^(s&7)).
// VT chunk (64 e x 64 s): block j <-> (e = j>>3, g = (j&7)^(e&7)).
__global__ __launch_bounds__(256, 4) void prep_kv(
    const float* __restrict__ Kg, const float* __restrict__ Vg,
    unsigned short* __restrict__ Kbf, unsigned short* __restrict__ VTbf) {
  __shared__ unsigned short vt[64 * 64];  // V^T tile in swizzled space

  const int t = threadIdx.x;
  const int id = blockIdx.x;
  const int bh = id & 63;  // id%8 = h -> same XCD as consumers
  const int sc = id >> 6;  // chunk 0..15
  const int h = bh & 7, b = bh >> 3;
  const int s0 = sc * CHUNK;

  const float* Kb = Kg + ((size_t)b * L_ + s0) * RSTRIDE + h * E_;
  const float* Vb = Vg + ((size_t)b * L_ + s0) * RSTRIDE + h * E_;
  unsigned short* Ko = Kbf + (size_t)(bh * NCH + sc) * CHUNK_USH;
  unsigned short* Vo = VTbf + (size_t)(bh * NCH + sc) * CHUNK_USH;

#pragma unroll
  for (int i = 0; i < 2; ++i) {
    const int j = t + 256 * i;  // 512 16B-blocks
    const int s = j >> 3;
    const int e8 = (j & 7) ^ (s & 7);
    const float* kp = Kb + (size_t)s * RSTRIDE + 8 * e8;
    float4 a = *reinterpret_cast<const float4*>(kp);
    float4 c = *reinterpret_cast<const float4*>(kp + 4);
    *reinterpret_cast<u16x4*>(&Ko[j * 8]) =
        (u16x4){f2bf(a.x), f2bf(a.y), f2bf(a.z), f2bf(a.w)};
    *reinterpret_cast<u16x4*>(&Ko[j * 8 + 4]) =
        (u16x4){f2bf(c.x), f2bf(c.y), f2bf(c.z), f2bf(c.w)};
  }
  {
    const int e = t & 63, w = t >> 6;
#pragma unroll
    for (int i = 0; i < 4; ++i) {
      const int s4 = 4 * w + 16 * i;
      const float* vp = Vb + (size_t)s4 * RSTRIDE + e;
      u16x4 u = {f2bf(vp[0]), f2bf(vp[RSTRIDE]), f2bf(vp[2 * RSTRIDE]),
                 f2bf(vp[3 * RSTRIDE])};
      *reinterpret_cast<u16x4*>(
          &vt[e * 64 + (((s4 >> 3) ^ (e & 7)) << 3) + (s4 & 7)]) = u;
    }
  }
  __syncthreads();
#pragma unroll
  for (int i = 0; i < 2; ++i) {
    const int j = t + 256 * i;  // swizzled space is block-linear
    u16x4 u0 = *reinterpret_cast<const u16x4*>(&vt[j * 8]);
    u16x4 u1 = *reinterpret_cast<const u16x4*>(&vt[j * 8 + 4]);
    *reinterpret_cast<u16x4*>(&Vo[j * 8]) = u0;
    *reinterpret_cast<u16x4*>(&Vo[j * 8 + 4]) = u1;
  }
}

// ---- z_pass: grid 4096 = (qb x ks) x bh; z-partials, no atomics ----
__global__ __launch_bounds__(256, 4) void z_pass(
    const float* __restrict__ Qg, const unsigned short* __restrict__ Kbf,
    float* __restrict__ zp) {
  __shared__ unsigned short sK[2][CHUNK_USH];  // 16KB

  const int t = threadIdx.x;
  const int lane = t & 63;
  const int w = t >> 6;
  const int col = lane & 15;
  const int kg = lane >> 4;

  const int id = blockIdx.x;  // id%8 = h -> XCD-pinned scratch in L2
  const int bh = id & 63;
  const int qk = id >> 6;   // 0..63
  const int qb = qk >> 2;   // 0..15
  const int ks = qk & 3;    // key quarter
  const int h = bh & 7;
  const int b = bh >> 3;
  const int q0 = qb * QBLK;
  const int c0 = ks * 4;  // this block's chunks: c0..c0+3

  const float sc_l2e = 0.125f * 1.44269504f;
  const float sl_l2e = exp2f(-(float)(h + 1) * 0.125f) * 1.44269504f;

  const unsigned short* Kc = Kbf + (size_t)bh * NCH * CHUNK_USH;

  short8 qf0, qf1;
  {
    const float* qp =
        Qg + ((size_t)b * L_ + q0 + 16 * w + col) * RSTRIDE + h * E_ + 8 * kg;
    qf0 = ldfrag(qp);
    qf1 = ldfrag(qp + 32);
  }
  const float kbias0 = sl_l2e * (float)(4 * kg - 1023) - 32.0f;

#define STAGEZ(c, dst)                                               \
  {                                                                  \
    const unsigned short* src = Kc + (size_t)(c)*CHUNK_USH;          \
    _Pragma("unroll") for (int i = 0; i < 2; ++i) {                  \
      const int seg = i * 4 + w;                                     \
      gld16(src + (size_t)(seg * 64 + lane) * 8, (dst) + seg * 512); \
    }                                                                \
  }

  float z0 = 0.f, z1 = 0.f, z2 = 0.f, z3 = 0.f;
  STAGEZ(c0, sK[0]);
  PIN();
  BAR_VM(0);
#pragma unroll
  for (int c = 0; c < 4; ++c) {
    if (c + 1 < 4) {
      STAGEZ(c0 + c + 1, sK[(c + 1) & 1]);
      PIN();
    }
    const int cc = c0 + c;
    const unsigned short* kb = sK[c & 1];
#pragma unroll
    for (int kt = 0; kt < 4; ++kt) {
      const int row = 16 * kt + col;
      short8 k0 = *reinterpret_cast<const short8*>(
          &kb[row * 64 + ((kg ^ (row & 7)) << 3)]);
      short8 k1 = *reinterpret_cast<const short8*>(
          &kb[row * 64 + (((kg + 4) ^ (row & 7)) << 3)]);
      f32x4 acc = {0.f, 0.f, 0.f, 0.f};
      acc = __builtin_amdgcn_mfma_f32_16x16x32_bf16(k0, qf0, acc, 0, 0, 0);
      acc = __builtin_amdgcn_mfma_f32_16x16x32_bf16(k1, qf1, acc, 0, 0, 0);
      const float base = fmaf((float)(CHUNK * cc + 16 * kt), sl_l2e, kbias0);
      z0 += __builtin_amdgcn_exp2f(fmaf(acc[0], sc_l2e, base));
      z1 += __builtin_amdgcn_exp2f(fmaf(acc[1], sc_l2e, base + sl_l2e));
      z2 += __builtin_amdgcn_exp2f(fmaf(acc[2], sc_l2e, base + 2.f * sl_l2e));
      z3 += __builtin_amdgcn_exp2f(fmaf(acc[3], sc_l2e, base + 3.f * sl_l2e));
    }
    BAR_VM(0);
  }
  float z = (z0 + z1) + (z2 + z3);
  z += __shfl_xor(z, 16, 64);
  z += __shfl_xor(z, 32, 64);  // all lanes: z-partial for q = col
  if (kg == 0) {
    zp[(size_t)(ks * 64 + bh) * L_ + q0 + 16 * w + col] = z;
  }
}

// ---- p_pass: R12 pass B verbatim + z-sum prologue ----
__global__ __launch_bounds__(256, 4) void p_pass(
    const float* __restrict__ Qg, const unsigned short* __restrict__ Kbf,
    const unsigned short* __restrict__ VTbf, const float* __restrict__ zp,
    float* __restrict__ Vout, float* __restrict__ Pout) {
  __shared__ unsigned short sBuf[4][CHUNK_USH];  // K in [0],[1]; VT [2],[3]

  const int t = threadIdx.x;
  const int lane = t & 63;
  const int w = t >> 6;
  const int col = lane & 15;
  const int kg = lane >> 4;

  const int id = blockIdx.x;  // id%8 = h -> XCD-pinned scratch in L2
  const int qb = id >> 6;
  const int bh = id & 63;
  const int h = bh & 7;
  const int b = bh >> 3;
  const int q0 = qb * QBLK;

  const float sc_l2e = 0.125f * 1.44269504f;
  const float sl_l2e = exp2f(-(float)(h + 1) * 0.125f) * 1.44269504f;

  const unsigned short* Kc = Kbf + (size_t)bh * NCH * CHUNK_USH;
  const unsigned short* Vc = VTbf + (size_t)bh * NCH * CHUNK_USH;

  short8 qf0, qf1;
  {
    const float* qp =
        Qg + ((size_t)b * L_ + q0 + 16 * w + col) * RSTRIDE + h * E_ + 8 * kg;
    qf0 = ldfrag(qp);
    qf1 = ldfrag(qp + 32);
  }
  const float kbias0 = sl_l2e * (float)(4 * kg - 1023) - 32.0f;

  // z-sum prologue: lane's q = col row
  float zsum;
  {
    const float* zb = zp + (size_t)bh * L_ + q0 + 16 * w + col;
    zsum = zb[0] + zb[64 * L_] + zb[2 * 64 * L_] + zb[3 * 64 * L_];
  }
  const float minv = 1.0f / zsum;

  f32x4 oacc[4];
#pragma unroll
  for (int et = 0; et < 4; ++et) oacc[et] = (f32x4){0.f, 0.f, 0.f, 0.f};

  float* Pb =
      Pout + ((size_t)(b * H_ + h) * L_ + q0 + 16 * w + col) * L_ + 4 * kg;

#define STAGE(srcbase, c, dst)                                       \
  {                                                                  \
    const unsigned short* src = (srcbase) + (size_t)(c)*CHUNK_USH;   \
    _Pragma("unroll") for (int i = 0; i < 2; ++i) {                  \
      const int seg = i * 4 + w;                                     \
      gld16(src + (size_t)(seg * 64 + lane) * 8, (dst) + seg * 512); \
    }                                                                \
  }

  STAGE(Kc, 0, sBuf[0]);
  STAGE(Vc, 0, sBuf[2]);
  PIN();
  BAR_VM(0);
  for (int c = 0; c < NCH; ++c) {
    if (c + 1 < NCH) {
      STAGE(Kc, c + 1, sBuf[(c + 1) & 1]);
      STAGE(Vc, c + 1, sBuf[2 + ((c + 1) & 1)]);
      PIN();  // pin the 4 loads ahead of this iteration's 4 P-stores
    }
    const unsigned short* kb = sBuf[c & 1];
    const unsigned short* vb = sBuf[2 + (c & 1)];
#pragma unroll
    for (int kt = 0; kt < 4; ++kt) {
      const int row = 16 * kt + col;
      short8 k0 = *reinterpret_cast<const short8*>(
          &kb[row * 64 + ((kg ^ (row & 7)) << 3)]);
      short8 k1 = *reinterpret_cast<const short8*>(
          &kb[row * 64 + (((kg + 4) ^ (row & 7)) << 3)]);
      f32x4 acc = {0.f, 0.f, 0.f, 0.f};
      acc = __builtin_amdgcn_mfma_f32_16x16x32_bf16(k0, qf0, acc, 0, 0, 0);
      acc = __builtin_amdgcn_mfma_f32_16x16x32_bf16(k1, qf1, acc, 0, 0, 0);
      // V^T fragments from LDS: e = 16et+col, s-block g0 = 2kt + (kg>>1)
      short4v vf[4];
      const int g0 = 2 * kt + (kg >> 1);
      const int so = 4 * (kg & 1);
#pragma unroll
      for (int et = 0; et < 4; ++et) {
        const int e = 16 * et + col;
        vf[et] = *reinterpret_cast<const short4v*>(
            &vb[e * 64 + ((g0 ^ (e & 7)) << 3) + so]);
      }
      const float base = fmaf((float)(CHUNK * c + 16 * kt), sl_l2e, kbias0);
      f32x4 pf;
      pf[0] = __builtin_amdgcn_exp2f(fmaf(acc[0], sc_l2e, base)) * minv;
      pf[1] =
          __builtin_amdgcn_exp2f(fmaf(acc[1], sc_l2e, base + sl_l2e)) * minv;
      pf[2] = __builtin_amdgcn_exp2f(fmaf(acc[2], sc_l2e, base + 2.f * sl_l2e)) *
              minv;
      pf[3] = __builtin_amdgcn_exp2f(fmaf(acc[3], sc_l2e, base + 3.f * sl_l2e)) *
              minv;
      // P store straight from D-frag (stays in flight across the barrier)
      *reinterpret_cast<f32x4*>(Pb + CHUNK * c + 16 * kt) = pf;
      // pack to bf16 A-frag (k = 4*kg + j == this lane's keys) and PV
      short4v pa = {(short)f2bf(pf[0]), (short)f2bf(pf[1]), (short)f2bf(pf[2]),
                    (short)f2bf(pf[3])};
#pragma unroll
      for (int et = 0; et < 4; ++et) oacc[et] = mfma16(pa, vf[et], oacc[et]);
    }
    // program order per iter (pinned): [4 stage loads][4 P-stores].
    BAR_VM(4);
  }

  // ---- write O: q = q0+16w+4kg+r, e = 16et+col (plain stores) ----
  float* Vo = Vout + (((size_t)b * L_ + q0 + 16 * w) * H_ + h) * E_;
#pragma unroll
  for (int et = 0; et < 4; ++et) {
#pragma unroll
    for (int r = 0; r < 4; ++r) {
      Vo[(4 * kg + r) * RSTRIDE + 16 * et + col] = oacc[et][r];
    }
  }
}

extern "C" void kernel_launch(void* const* d_in, const int* in_sizes, int n_in,
                              void* d_out, int out_size, void* d_ws,
                              size_t ws_size, hipStream_t stream) {
  const float* Q = (const float*)d_in[0];
  const float* K = (const float*)d_in[1];
  const float* V = (const float*)d_in[2];
  float* out = (float*)d_out;
  float* Vo = out;                              // [B,L,H,E]
  float* Po = out + (size_t)B_ * L_ * H_ * E_;  // [B,H,L,L]
  unsigned short* Kbf = (unsigned short*)d_ws;             // 8 MB
  unsigned short* VTbf = Kbf + (size_t)B_ * H_ * L_ * E_;  // 8 MB
  float* zp = (float*)(VTbf + (size_t)B_ * H_ * L_ * E_);  // 1 MB: [4][64][L]
  hipLaunchKernelGGL(prep_kv, dim3(NCH * B_ * H_), dim3(256), 0, stream, K, V,
                     Kbf, VTbf);
  hipLaunchKernelGGL(z_pass, dim3(16 * 4 * 64), dim3(256), 0, stream, Q, Kbf,
                     zp);
  hipLaunchKernelGGL(p_pass, dim3((L_ / QBLK) * H_ * B_), dim3(256), 0, stream,
                     Q, Kbf, VTbf, zp, Vo, Po);
}